// Round 13
// baseline (261.830 us; speedup 1.0000x reference)
//
#include <hip/hip_runtime.h>
#include <math.h>

// MS-SSIM loss, 5 levels, 11-tap separable Gaussian (sigma=1.5), VALID padding.
// Round 13: barrier-free wave-modular row streaming.
// Each WAVE independently owns a 64-output-col band (+10 halo) of a row strip,
// with wave-private double-buffered LDS row slots (2 rows per slot). Schedule
// per iteration is round 8's proven one: write_slot(other) [vmcnt wait], issue
// next loads, h-conv read current slot, ring v-accum, emit, pool. One wave's
// DS ops complete in order -> no __syncthreads anywhere. Waves stall
// independently (16/CU), covering HBM latency that the r8 barrier convoy
// exposed. r9 proved wave-private correctness; r8 proved the schedule.
// 4-map transform (a=x+y, b=x-y -> P,Q,U,V), x2-rescaled emit algebra (exact).

struct GWin { float w[11]; };

__global__ __launch_bounds__(256)
void ssim_rows_kernel(const float* __restrict__ X, const float* __restrict__ Y,
                      float* __restrict__ poolX, float* __restrict__ poolY,
                      float* __restrict__ accum,   // [0..95]=ssim, [96..191]=cs
                      int S, int outS, int doPool, int rps, int nBands, int nStrips,
                      GWin gw)
{
    __shared__ float2 ab[4][2][2][76];   // [wave][slot][row01][floatcol] = {a,b}

    const int ch  = blockIdx.z;
    const int w   = threadIdx.x >> 6;
    const int ln  = threadIdx.x & 63;
    const int wid = blockIdx.x * 4 + w;

    const int band  = wid % nBands;
    const int strip = wid / nBands;
    if (strip >= nStrips) return;        // no barriers -> early exit is safe

    const int gb  = band * 64;           // wave's base output float-col
    const int oy0 = strip * rps;
    const int halfS = S >> 1;

    int rowsOut = outS - oy0; if (rowsOut > rps) rowsOut = rps;
    const int NIT = (rowsOut + 11) >> 1; // iterations (2 input rows each)

    const float* Xc = X + (size_t)ch * S * S;
    const float* Yc = Y + (size_t)ch * S * S;

    // staging decode: 74 float2-col tasks over 2 rows (37 per row)
    const int  r0_ = (ln < 37) ? 0 : 1;
    const int  c0  = (ln < 37) ? ln : ln - 37;   // float2 task index in row
    const bool hasT1 = (ln < 10);
    const int  c1  = 27 + ln;                    // extra task: row 1, idx 27..36

    float2 sx0, sy0, sx1, sy1;           // prefetched global data

    auto issue = [&](int baseRow) {      // load rows baseRow, baseRow+1 -> regs
        {
            int gr = baseRow + r0_; if (gr > S - 1) gr = S - 1;
            const float* xr = Xc + (size_t)gr * S;
            const float* yr = Yc + (size_t)gr * S;
            int gc = gb + 2 * c0;
            if (gc + 1 < S) {
                sx0 = *reinterpret_cast<const float2*>(xr + gc);
                sy0 = *reinterpret_cast<const float2*>(yr + gc);
            } else {
                int g0 = gc < S ? gc : S - 1;
                sx0.x = xr[g0]; sx0.y = xr[S - 1];
                sy0.x = yr[g0]; sy0.y = yr[S - 1];
            }
        }
        if (hasT1) {
            int gr = baseRow + 1; if (gr > S - 1) gr = S - 1;
            const float* xr = Xc + (size_t)gr * S;
            const float* yr = Yc + (size_t)gr * S;
            int gc = gb + 2 * c1;
            if (gc + 1 < S) {
                sx1 = *reinterpret_cast<const float2*>(xr + gc);
                sy1 = *reinterpret_cast<const float2*>(yr + gc);
            } else {
                int g0 = gc < S ? gc : S - 1;
                sx1.x = xr[g0]; sx1.y = xr[S - 1];
                sy1.x = yr[g0]; sy1.y = yr[S - 1];
            }
        }
    };
    auto write_slot = [&](int sl) {      // regs -> wave-private LDS, {a,b} interleaved
        float4 v0;
        v0.x = sx0.x + sy0.x; v0.y = sx0.x - sy0.x;
        v0.z = sx0.y + sy0.y; v0.w = sx0.y - sy0.y;
        *reinterpret_cast<float4*>(&ab[w][sl][r0_][2 * c0]) = v0;
        if (hasT1) {
            float4 v1;
            v1.x = sx1.x + sy1.x; v1.y = sx1.x - sy1.x;
            v1.z = sx1.y + sy1.y; v1.w = sx1.y - sy1.y;
            *reinterpret_cast<float4*>(&ab[w][sl][1][2 * c1]) = v1;
        }
    };

    // pending v-conv partials: 12 slots x {P,Q} + {U,V}
    float2 pendPQ[12], pendUV[12];
    #pragma unroll
    for (int i = 0; i < 12; ++i) { pendPQ[i] = make_float2(0.f, 0.f); pendUV[i] = make_float2(0.f, 0.f); }

    float ssum = 0.f, csum = 0.f;
    const float C1x2 = 2e-4f, C2x2 = 1.8e-3f;
    const bool colOK = (gb + ln) < outS;

    // prologue
    issue(oy0);
    write_slot(0);
    issue(oy0 + 2);

    for (int k = 0; k < NIT; ++k) {
        const int sl = k & 1;
        if (k + 1 < NIT) {
            write_slot(sl ^ 1);          // rows oy0+2(k+1) (regs from iter k-1)
            if (k + 3 <= NIT) issue(oy0 + 2 * (k + 2));
        }

        // ---- h-conv for the 2 staged rows: one ds_read_b64 per tap ----
        float2 hPQ0 = make_float2(0.f, 0.f), hUV0 = make_float2(0.f, 0.f);
        float2 hPQ1 = make_float2(0.f, 0.f), hUV1 = make_float2(0.f, 0.f);
        #pragma unroll
        for (int t = 0; t < 11; ++t) {
            float wt = gw.w[t];
            float2 v = ab[w][sl][0][ln + t];
            hPQ0.x = fmaf(wt, v.x, hPQ0.x);
            hPQ0.y = fmaf(wt, v.y, hPQ0.y);
            hUV0.x = fmaf(wt * v.x, v.x, hUV0.x);
            hUV0.y = fmaf(wt * v.y, v.y, hUV0.y);
        }
        #pragma unroll
        for (int t = 0; t < 11; ++t) {
            float wt = gw.w[t];
            float2 v = ab[w][sl][1][ln + t];
            hPQ1.x = fmaf(wt, v.x, hPQ1.x);
            hPQ1.y = fmaf(wt, v.y, hPQ1.y);
            hUV1.x = fmaf(wt * v.x, v.x, hUV1.x);
            hUV1.y = fmaf(wt * v.y, v.y, hUV1.y);
        }

        // ---- v-accumulate into pending ring ----
        #pragma unroll
        for (int j = 0; j <= 10; ++j) {          // row 2k: w[10-j] -> slot j
            float wt = gw.w[10 - j];
            pendPQ[j].x = fmaf(wt, hPQ0.x, pendPQ[j].x);
            pendPQ[j].y = fmaf(wt, hPQ0.y, pendPQ[j].y);
            pendUV[j].x = fmaf(wt, hUV0.x, pendUV[j].x);
            pendUV[j].y = fmaf(wt, hUV0.y, pendUV[j].y);
        }
        #pragma unroll
        for (int j = 1; j <= 11; ++j) {          // row 2k+1: w[11-j] -> slot j
            float wt = gw.w[11 - j];
            pendPQ[j].x = fmaf(wt, hPQ1.x, pendPQ[j].x);
            pendPQ[j].y = fmaf(wt, hPQ1.y, pendPQ[j].y);
            pendUV[j].x = fmaf(wt, hUV1.x, pendUV[j].x);
            pendUV[j].y = fmaf(wt, hUV1.y, pendUV[j].y);
        }

        // ---- emit 2 finished output rows (x2-rescaled algebra, exact) ----
        #pragma unroll
        for (int e = 0; e < 2; ++e) {
            int rel = 2 * k - 10 + e;
            float p = pendPQ[e].x, q = pendPQ[e].y;
            float u = pendUV[e].x, v = pendUV[e].y;
            float p2 = p * p, q2 = q * q;
            float A = p2 - q2;                         // 2*(2 mu12)
            float csn = (u - v - A) + C2x2;            // 2*(2 sigma12) + 2C2
            float csd = (u + v - p2 - q2) + C2x2;
            float cs  = csn * __builtin_amdgcn_rcpf(csd);
            float ss  = (A + C1x2) * __builtin_amdgcn_rcpf(p2 + q2 + C1x2) * cs;
            if ((unsigned)rel < (unsigned)rowsOut && colOK) { ssum += ss; csum += cs; }
        }

        // ---- shift ring by 2 slots ----
        #pragma unroll
        for (int j = 0; j < 10; ++j) { pendPQ[j] = pendPQ[j + 2]; pendUV[j] = pendUV[j + 2]; }
        pendPQ[10] = make_float2(0.f, 0.f); pendUV[10] = make_float2(0.f, 0.f);
        pendPQ[11] = make_float2(0.f, 0.f); pendUV[11] = make_float2(0.f, 0.f);

        // ---- 2x2 pool of the 2 staged rows (wave-private, before overwrite) ----
        if (doPool && ln < 32 && k < (rps >> 1)) {
            float4 q0 = *reinterpret_cast<const float4*>(&ab[w][sl][0][2 * ln]);
            float4 q1 = *reinterpret_cast<const float4*>(&ab[w][sl][1][2 * ln]);
            float sa = q0.x + q0.z + q1.x + q1.z;
            float sb = q0.y + q0.w + q1.y + q1.w;
            int pc = (gb >> 1) + ln;
            if (pc < halfS) {
                int prow = (oy0 >> 1) + k;
                size_t o = (size_t)ch * halfS * halfS + (size_t)prow * halfS + pc;
                poolX[o] = 0.125f * (sa + sb);
                poolY[o] = 0.125f * (sa - sb);
            }
        }
    }

    // ---- per-wave reduction + atomic accumulate (no barrier) ----
    for (int off = 32; off > 0; off >>= 1) {
        ssum += __shfl_down(ssum, off);
        csum += __shfl_down(csum, off);
    }
    if (ln == 0) {
        atomicAdd(&accum[ch], ssum);
        atomicAdd(&accum[96 + ch], csum);
    }
}

__global__ void finalize_kernel(const float* __restrict__ accum, float* __restrict__ out)
{
    __shared__ float red[2];
    const int t = threadIdx.x;   // 128 threads
    const float w[5]   = {0.0448f, 0.2856f, 0.3001f, 0.2363f, 0.1333f};
    const float inv[5] = {1.f / (502.f * 502.f), 1.f / (246.f * 246.f),
                          1.f / (118.f * 118.f), 1.f / (54.f * 54.f),
                          1.f / (22.f * 22.f)};
    float ms = 0.f;
    if (t < 96) {
        ms = 1.f;
        #pragma unroll
        for (int l = 0; l < 5; ++l) {
            float v = (l < 4) ? accum[l * 192 + 96 + t] : accum[l * 192 + t];
            v *= inv[l];
            v = fmaxf(v, 0.f);
            ms *= powf(v, w[l]);
        }
    }
    for (int off = 32; off > 0; off >>= 1) ms += __shfl_down(ms, off);
    int wid = t >> 6, lane = t & 63;
    if (lane == 0) red[wid] = ms;
    __syncthreads();
    if (t == 0) out[0] = 1.f - (red[0] + red[1]) * (1.f / 96.f);
}

extern "C" void kernel_launch(void* const* d_in, const int* in_sizes, int n_in,
                              void* d_out, int out_size, void* d_ws, size_t ws_size,
                              hipStream_t stream)
{
    (void)in_sizes; (void)n_in; (void)out_size; (void)ws_size;
    const float* X = (const float*)d_in[0];
    const float* Y = (const float*)d_in[1];
    float* out = (float*)d_out;
    float* ws  = (float*)d_ws;

    // Gaussian window (size 11, sigma 1.5), normalized
    GWin gw;
    {
        double g[11], s = 0.0;
        for (int i = 0; i < 11; ++i) { double d = i - 5; g[i] = exp(-(d * d) / 4.5); s += g[i]; }
        for (int i = 0; i < 11; ++i) gw.w[i] = (float)(g[i] / s);
    }

    // workspace layout (floats)
    float* accum = ws;                 // 5 levels * 192
    size_t off = 1024;
    float* p1x = ws + off; off += (size_t)96 * 256 * 256;
    float* p1y = ws + off; off += (size_t)96 * 256 * 256;
    float* p2x = ws + off; off += (size_t)96 * 128 * 128;
    float* p2y = ws + off; off += (size_t)96 * 128 * 128;
    float* p3x = ws + off; off += (size_t)96 * 64 * 64;
    float* p3y = ws + off; off += (size_t)96 * 64 * 64;
    float* p4x = ws + off; off += (size_t)96 * 32 * 32;
    float* p4y = ws + off; off += (size_t)96 * 32 * 32;

    hipMemsetAsync(accum, 0, 5 * 192 * sizeof(float), stream);

    auto launch = [&](const float* x, const float* y, float* px_, float* py_,
                      float* acc, int S, int outS, int pool, int rps) {
        int nBands  = (S + 63) / 64;
        int nStrips = (outS + rps - 1) / rps;
        int waves   = nBands * nStrips;
        int blocks  = (waves + 3) / 4;
        dim3 g(blocks, 1, 96);
        ssim_rows_kernel<<<g, 256, 0, stream>>>(x, y, px_, py_, acc, S, outS, pool,
                                                rps, nBands, nStrips, gw);
    };

    // nStrips * rps == S guaranteed per level (pool coverage): 8*64, 8*32, 4*32, 4*16, 1*22(+pad)
    launch(X,   Y,   p1x, p1y, accum + 0,   512, 502, 1, 64);
    launch(p1x, p1y, p2x, p2y, accum + 192, 256, 246, 1, 32);
    launch(p2x, p2y, p3x, p3y, accum + 384, 128, 118, 1, 32);
    launch(p3x, p3y, p4x, p4y, accum + 576, 64,  54,  1, 16);
    launch(p4x, p4y, nullptr, nullptr, accum + 768, 32, 22, 0, 22);

    finalize_kernel<<<1, 128, 0, stream>>>(accum, out);
}

// Round 14
// 240.279 us; speedup vs baseline: 1.0897x; 1.0897x over previous
//
#include <hip/hip_runtime.h>
#include <math.h>

// MS-SSIM loss, 5 levels, 11-tap separable Gaussian (sigma=1.5), VALID padding.
// Round 14: round-8 structure with a surgical reorder: the h-conv/pool reads of
// slot sl and ALL ring/emit VALU run FIRST; write_slot(sl^1) (which carries the
// s_waitcnt vmcnt(0) for the prefetched loads) moves to the BOTTOM of the
// iteration, just before the barrier. This removes the false ordering where the
// in-order DS pipe forced every h-conv ds_read to queue behind a vmcnt-drained
// ds_write. Loads now get a full compute phase of latency cover.
// + rowsOut-trimmed NIT (tail strips), per-wave atomic reduce, bigger strips
//   (L0 rps=128, L1 64) to amortize the 5-iter prologue and halo re-reads.
// 4-map transform (a=x+y, b=x-y -> P,Q,U,V), x2-rescaled emit algebra (exact).

#define RWF 272          // staged float-cols per row: 256 band + 10 halo + pad

struct GWin { float w[11]; };

__global__ __launch_bounds__(256)
void ssim_rows_kernel(const float* __restrict__ X, const float* __restrict__ Y,
                      float* __restrict__ poolX, float* __restrict__ poolY,
                      float* __restrict__ accum,   // [0..95]=ssim, [96..191]=cs
                      int S, int outS, int doPool, int rps, GWin gw)
{
    __shared__ float2 ab[2][2][RWF];     // [slot][row01][floatcol] = {a, b}

    const int ch  = blockIdx.z;
    const int oy0 = blockIdx.x * rps;
    const int cb0 = blockIdx.y * 256;
    const int tid = threadIdx.x;
    const int halfS = S >> 1;

    int rowsOut = outS - oy0; if (rowsOut > rps) rowsOut = rps;
    const int NIT = (rowsOut + 11) >> 1;     // iterations (2 input rows each)

    const float* Xc = X + (size_t)ch * S * S;
    const float* Yc = Y + (size_t)ch * S * S;

    // staging task decode: 272 float2-col tasks over 2 rows (136 per row)
    const int  r0_ = (tid < 136) ? 0 : 1;
    const int  c20 = (tid < 136) ? tid : tid - 136;
    const bool hasT1 = (tid < 16);
    const int  c21 = 120 + tid;          // extra task: row 1, c2 in [120,136)

    float2 sx0, sy0, sx1, sy1;           // prefetched global data

    auto issue = [&](int baseRow) {      // load rows baseRow, baseRow+1 -> regs
        {
            int gr = baseRow + r0_; if (gr > S - 1) gr = S - 1;
            const float* xr = Xc + (size_t)gr * S;
            const float* yr = Yc + (size_t)gr * S;
            int gc = cb0 + 2 * c20;
            if (gc + 1 < S) {
                sx0 = *reinterpret_cast<const float2*>(xr + gc);
                sy0 = *reinterpret_cast<const float2*>(yr + gc);
            } else {
                int g0 = gc < S ? gc : S - 1;
                sx0.x = xr[g0]; sx0.y = xr[S - 1];
                sy0.x = yr[g0]; sy0.y = yr[S - 1];
            }
        }
        if (hasT1) {
            int gr = baseRow + 1; if (gr > S - 1) gr = S - 1;
            const float* xr = Xc + (size_t)gr * S;
            const float* yr = Yc + (size_t)gr * S;
            int gc = cb0 + 2 * c21;
            if (gc + 1 < S) {
                sx1 = *reinterpret_cast<const float2*>(xr + gc);
                sy1 = *reinterpret_cast<const float2*>(yr + gc);
            } else {
                int g0 = gc < S ? gc : S - 1;
                sx1.x = xr[g0]; sx1.y = xr[S - 1];
                sy1.x = yr[g0]; sy1.y = yr[S - 1];
            }
        }
    };
    auto write_slot = [&](int sl) {      // regs -> LDS interleaved {a,b}: one b128 per task
        float4 v0;
        v0.x = sx0.x + sy0.x; v0.y = sx0.x - sy0.x;
        v0.z = sx0.y + sy0.y; v0.w = sx0.y - sy0.y;
        *reinterpret_cast<float4*>(&ab[sl][r0_][2 * c20]) = v0;
        if (hasT1) {
            float4 v1;
            v1.x = sx1.x + sy1.x; v1.y = sx1.x - sy1.x;
            v1.z = sx1.y + sy1.y; v1.w = sx1.y - sy1.y;
            *reinterpret_cast<float4*>(&ab[sl][1][2 * c21]) = v1;
        }
    };

    // pending v-conv partials: 12 slots x {P,Q} + {U,V}
    float2 pendPQ[12], pendUV[12];
    #pragma unroll
    for (int i = 0; i < 12; ++i) { pendPQ[i] = make_float2(0.f, 0.f); pendUV[i] = make_float2(0.f, 0.f); }

    float ssum = 0.f, csum = 0.f;
    const float C1x2 = 2e-4f, C2x2 = 1.8e-3f;
    const bool colOK = (cb0 + tid) < outS;

    // prologue
    issue(oy0);
    write_slot(0);
    issue(oy0 + 2);
    __syncthreads();

    for (int k = 0; k < NIT; ++k) {
        const int sl = k & 1;

        // ---- h-conv for the 2 staged rows: one ds_read_b64 per tap ----
        // (reads issue immediately after the barrier; no vmcnt drain in front)
        float2 hPQ0 = make_float2(0.f, 0.f), hUV0 = make_float2(0.f, 0.f);
        float2 hPQ1 = make_float2(0.f, 0.f), hUV1 = make_float2(0.f, 0.f);
        #pragma unroll
        for (int t = 0; t < 11; ++t) {
            float wt = gw.w[t];
            float2 v = ab[sl][0][tid + t];
            hPQ0.x = fmaf(wt, v.x, hPQ0.x);
            hPQ0.y = fmaf(wt, v.y, hPQ0.y);
            hUV0.x = fmaf(wt * v.x, v.x, hUV0.x);
            hUV0.y = fmaf(wt * v.y, v.y, hUV0.y);
        }
        #pragma unroll
        for (int t = 0; t < 11; ++t) {
            float wt = gw.w[t];
            float2 v = ab[sl][1][tid + t];
            hPQ1.x = fmaf(wt, v.x, hPQ1.x);
            hPQ1.y = fmaf(wt, v.y, hPQ1.y);
            hUV1.x = fmaf(wt * v.x, v.x, hUV1.x);
            hUV1.y = fmaf(wt * v.y, v.y, hUV1.y);
        }

        // ---- 2x2 pool of the 2 staged rows (reads slot sl) ----
        if (doPool && tid < 128 && k < (rps >> 1)) {
            float4 q0 = *reinterpret_cast<const float4*>(&ab[sl][0][2 * tid]);
            float4 q1 = *reinterpret_cast<const float4*>(&ab[sl][1][2 * tid]);
            float sa = q0.x + q0.z + q1.x + q1.z;
            float sb = q0.y + q0.w + q1.y + q1.w;
            int pc = (cb0 >> 1) + tid;
            if (pc < halfS) {
                int prow = (oy0 >> 1) + k;
                size_t o = (size_t)ch * halfS * halfS + (size_t)prow * halfS + pc;
                poolX[o] = 0.125f * (sa + sb);
                poolY[o] = 0.125f * (sa - sb);
            }
        }

        // ---- v-accumulate into pending ring (pure VALU, covers load latency) ----
        #pragma unroll
        for (int j = 0; j <= 10; ++j) {          // row 2k: w[10-j] -> slot j
            float wt = gw.w[10 - j];
            pendPQ[j].x = fmaf(wt, hPQ0.x, pendPQ[j].x);
            pendPQ[j].y = fmaf(wt, hPQ0.y, pendPQ[j].y);
            pendUV[j].x = fmaf(wt, hUV0.x, pendUV[j].x);
            pendUV[j].y = fmaf(wt, hUV0.y, pendUV[j].y);
        }
        #pragma unroll
        for (int j = 1; j <= 11; ++j) {          // row 2k+1: w[11-j] -> slot j
            float wt = gw.w[11 - j];
            pendPQ[j].x = fmaf(wt, hPQ1.x, pendPQ[j].x);
            pendPQ[j].y = fmaf(wt, hPQ1.y, pendPQ[j].y);
            pendUV[j].x = fmaf(wt, hUV1.x, pendUV[j].x);
            pendUV[j].y = fmaf(wt, hUV1.y, pendUV[j].y);
        }

        // ---- emit 2 finished output rows (x2-rescaled algebra, exact) ----
        #pragma unroll
        for (int e = 0; e < 2; ++e) {
            int rel = 2 * k - 10 + e;
            float p = pendPQ[e].x, q = pendPQ[e].y;
            float u = pendUV[e].x, v = pendUV[e].y;
            float p2 = p * p, q2 = q * q;
            float A = p2 - q2;                         // 2*(2 mu12)
            float csn = (u - v - A) + C2x2;            // 2*(2 sigma12) + 2C2
            float csd = (u + v - p2 - q2) + C2x2;
            float cs  = csn * __builtin_amdgcn_rcpf(csd);
            float ss  = (A + C1x2) * __builtin_amdgcn_rcpf(p2 + q2 + C1x2) * cs;
            if ((unsigned)rel < (unsigned)rowsOut && colOK) { ssum += ss; csum += cs; }
        }

        // ---- shift ring by 2 slots ----
        #pragma unroll
        for (int j = 0; j < 10; ++j) { pendPQ[j] = pendPQ[j + 2]; pendUV[j] = pendUV[j + 2]; }
        pendPQ[10] = make_float2(0.f, 0.f); pendUV[10] = make_float2(0.f, 0.f);
        pendPQ[11] = make_float2(0.f, 0.f); pendUV[11] = make_float2(0.f, 0.f);

        // ---- NOW drain vmcnt & stage next rows; then refill the pipe ----
        if (k + 1 < NIT) {
            write_slot(sl ^ 1);          // rows oy0+2(k+1) (regs from iter k-1)
            if (k + 2 < NIT) issue(oy0 + 2 * (k + 2));
        }

        __syncthreads();
    }

    // ---- per-wave reduction + atomic accumulate ----
    for (int off = 32; off > 0; off >>= 1) {
        ssum += __shfl_down(ssum, off);
        csum += __shfl_down(csum, off);
    }
    if ((tid & 63) == 0) {
        atomicAdd(&accum[ch], ssum);
        atomicAdd(&accum[96 + ch], csum);
    }
}

__global__ void finalize_kernel(const float* __restrict__ accum, float* __restrict__ out)
{
    __shared__ float red[2];
    const int t = threadIdx.x;   // 128 threads
    const float w[5]   = {0.0448f, 0.2856f, 0.3001f, 0.2363f, 0.1333f};
    const float inv[5] = {1.f / (502.f * 502.f), 1.f / (246.f * 246.f),
                          1.f / (118.f * 118.f), 1.f / (54.f * 54.f),
                          1.f / (22.f * 22.f)};
    float ms = 0.f;
    if (t < 96) {
        ms = 1.f;
        #pragma unroll
        for (int l = 0; l < 5; ++l) {
            float v = (l < 4) ? accum[l * 192 + 96 + t] : accum[l * 192 + t];
            v *= inv[l];
            v = fmaxf(v, 0.f);
            ms *= powf(v, w[l]);
        }
    }
    for (int off = 32; off > 0; off >>= 1) ms += __shfl_down(ms, off);
    int wid = t >> 6, lane = t & 63;
    if (lane == 0) red[wid] = ms;
    __syncthreads();
    if (t == 0) out[0] = 1.f - (red[0] + red[1]) * (1.f / 96.f);
}

extern "C" void kernel_launch(void* const* d_in, const int* in_sizes, int n_in,
                              void* d_out, int out_size, void* d_ws, size_t ws_size,
                              hipStream_t stream)
{
    (void)in_sizes; (void)n_in; (void)out_size; (void)ws_size;
    const float* X = (const float*)d_in[0];
    const float* Y = (const float*)d_in[1];
    float* out = (float*)d_out;
    float* ws  = (float*)d_ws;

    // Gaussian window (size 11, sigma 1.5), normalized
    GWin gw;
    {
        double g[11], s = 0.0;
        for (int i = 0; i < 11; ++i) { double d = i - 5; g[i] = exp(-(d * d) / 4.5); s += g[i]; }
        for (int i = 0; i < 11; ++i) gw.w[i] = (float)(g[i] / s);
    }

    // workspace layout (floats)
    float* accum = ws;                 // 5 levels * 192
    size_t off = 1024;
    float* p1x = ws + off; off += (size_t)96 * 256 * 256;
    float* p1y = ws + off; off += (size_t)96 * 256 * 256;
    float* p2x = ws + off; off += (size_t)96 * 128 * 128;
    float* p2y = ws + off; off += (size_t)96 * 128 * 128;
    float* p3x = ws + off; off += (size_t)96 * 64 * 64;
    float* p3y = ws + off; off += (size_t)96 * 64 * 64;
    float* p4x = ws + off; off += (size_t)96 * 32 * 32;
    float* p4y = ws + off; off += (size_t)96 * 32 * 32;

    hipMemsetAsync(accum, 0, 5 * 192 * sizeof(float), stream);

    auto launch = [&](const float* x, const float* y, float* px_, float* py_,
                      float* acc, int S, int outS, int pool, int rps) {
        dim3 g((outS + rps - 1) / rps, (S + 255) / 256, 96);
        ssim_rows_kernel<<<g, 256, 0, stream>>>(x, y, px_, py_, acc, S, outS, pool, rps, gw);
    };

    // strip heights: amortize the 5-iter prologue; pool coverage verified per level
    launch(X,   Y,   p1x, p1y, accum + 0,   512, 502, 1, 128);
    launch(p1x, p1y, p2x, p2y, accum + 192, 256, 246, 1, 64);
    launch(p2x, p2y, p3x, p3y, accum + 384, 128, 118, 1, 32);
    launch(p3x, p3y, p4x, p4y, accum + 576, 64,  54,  1, 32);
    launch(p4x, p4y, nullptr, nullptr, accum + 768, 32, 22, 0, 32);

    finalize_kernel<<<1, 128, 0, stream>>>(accum, out);
}

// Round 15
// 183.248 us; speedup vs baseline: 1.4288x; 1.3112x over previous
//
#include <hip/hip_runtime.h>
#include <math.h>

// MS-SSIM loss, 5 levels, 11-tap separable Gaussian (sigma=1.5), VALID padding.
// Round 15: DS-bytes-halving rewrite (DS pipe measured ~90% saturated in r8-r14).
// - Thread owns 2 adjacent output cols; LDS stores col-pairs as float4 {a,b,a,b}
//   so h-conv taps are 6 aligned ds_read_b128 per row (48B/col-row vs 88B).
// - Full-row bands: no column halo, no col clamps; staging = 1 b128 write/row.
// - Squares shared between the 2 cols; pool computed from registers.
// - Small levels: tpc=S/2 threads per channel, nsub=256/tpc channels per block.
// - r14 schedule: compute first, write_slot+issue at bottom, 1 barrier/iter.
// 4-map transform (a=x+y, b=x-y -> P,Q,U,V), x2-rescaled emit algebra (exact).

struct GWin { float w[11]; };

__global__ __launch_bounds__(256)
void ssim_rows_kernel(const float* __restrict__ X, const float* __restrict__ Y,
                      float* __restrict__ poolX, float* __restrict__ poolY,
                      float* __restrict__ accum,   // [0..95]=ssim, [96..191]=cs
                      int S, int outS, int doPool, int rps, int tpcLog, GWin gw)
{
    __shared__ float4 ab[2][2][264];     // [slot][row01][col-pair unit {a,b,a,b}]

    const int tid = threadIdx.x;
    const int tpc = 1 << tpcLog;         // threads per channel = S/2
    const int lt  = tid & (tpc - 1);
    const int sub = tid >> tpcLog;
    const int ch  = blockIdx.z * (256 >> tpcLog) + sub;
    const int oy0 = blockIdx.x * rps;
    const int halfS = S >> 1;
    const int gc  = 2 * lt;              // thread's base input/output column

    int rowsOut = outS - oy0; if (rowsOut > rps) rowsOut = rps;
    const int NIT = (rowsOut + 11) >> 1; // iterations (2 input rows each)

    const float* Xc = X + (size_t)ch * S * S;
    const float* Yc = Y + (size_t)ch * S * S;

    float2 sx0, sy0, sx1, sy1;           // prefetched global data (2 rows)

    auto issue = [&](int baseRow) {
        int gr0 = baseRow;     if (gr0 > S - 1) gr0 = S - 1;
        int gr1 = baseRow + 1; if (gr1 > S - 1) gr1 = S - 1;
        sx0 = *reinterpret_cast<const float2*>(Xc + (size_t)gr0 * S + gc);
        sy0 = *reinterpret_cast<const float2*>(Yc + (size_t)gr0 * S + gc);
        sx1 = *reinterpret_cast<const float2*>(Xc + (size_t)gr1 * S + gc);
        sy1 = *reinterpret_cast<const float2*>(Yc + (size_t)gr1 * S + gc);
    };
    auto write_slot = [&](int sl) {      // one b128 per row: {a0,b0,a1,b1}
        ab[sl][0][tid] = make_float4(sx0.x + sy0.x, sx0.x - sy0.x,
                                     sx0.y + sy0.y, sx0.y - sy0.y);
        ab[sl][1][tid] = make_float4(sx1.x + sy1.x, sx1.x - sy1.x,
                                     sx1.y + sy1.y, sx1.y - sy1.y);
    };

    // pending v-conv partials: [col][slot], all static-indexed
    float pendP[2][12], pendQ[2][12], pendU[2][12], pendV[2][12];
    #pragma unroll
    for (int c = 0; c < 2; ++c)
        #pragma unroll
        for (int j = 0; j < 12; ++j) { pendP[c][j] = 0.f; pendQ[c][j] = 0.f; pendU[c][j] = 0.f; pendV[c][j] = 0.f; }

    float ssum = 0.f, csum = 0.f;
    const float C1x2 = 2e-4f, C2x2 = 1.8e-3f;
    const bool ok0 = (gc    ) < outS;
    const bool ok1 = (gc + 1) < outS;

    // prologue (zero the 8 overrun units read by the last threads)
    if (tid < 8) {
        float4 z = make_float4(0.f, 0.f, 0.f, 0.f);
        ab[0][0][256 + tid] = z; ab[0][1][256 + tid] = z;
        ab[1][0][256 + tid] = z; ab[1][1][256 + tid] = z;
    }
    issue(oy0);
    write_slot(0);
    issue(oy0 + 2);
    __syncthreads();

    for (int k = 0; k < NIT; ++k) {
        const int sl = k & 1;

        // ---- h-conv for both staged rows: 6 ds_read_b128 per row ----
        float hP[2][2], hQ[2][2], hU[2][2], hV[2][2];   // [row][col]
        float4 u0save[2];
        #pragma unroll
        for (int r = 0; r < 2; ++r) {
            const float4* bp = &ab[sl][r][tid];
            float4 u[6];
            #pragma unroll
            for (int i = 0; i < 6; ++i) u[i] = bp[i];
            u0save[r] = u[0];
            const float* v = reinterpret_cast<const float*>(u);  // v[2j]=a_j, v[2j+1]=b_j
            float sqa[12], sqb[12];
            #pragma unroll
            for (int j = 0; j < 12; ++j) {
                float a = v[2 * j], b = v[2 * j + 1];
                sqa[j] = a * a; sqb[j] = b * b;
            }
            float P0 = 0.f, Q0 = 0.f, U0 = 0.f, V0 = 0.f;
            float P1 = 0.f, Q1 = 0.f, U1 = 0.f, V1 = 0.f;
            #pragma unroll
            for (int t = 0; t < 11; ++t) {
                float wt = gw.w[t];
                P0 = fmaf(wt, v[2 * t],     P0);
                Q0 = fmaf(wt, v[2 * t + 1], Q0);
                U0 = fmaf(wt, sqa[t],       U0);
                V0 = fmaf(wt, sqb[t],       V0);
                P1 = fmaf(wt, v[2 * t + 2], P1);
                Q1 = fmaf(wt, v[2 * t + 3], Q1);
                U1 = fmaf(wt, sqa[t + 1],   U1);
                V1 = fmaf(wt, sqb[t + 1],   V1);
            }
            hP[r][0] = P0; hQ[r][0] = Q0; hU[r][0] = U0; hV[r][0] = V0;
            hP[r][1] = P1; hQ[r][1] = Q1; hU[r][1] = U1; hV[r][1] = V1;
        }

        // ---- v-accumulate into pending rings ----
        #pragma unroll
        for (int c = 0; c < 2; ++c) {
            #pragma unroll
            for (int j = 0; j <= 10; ++j) {          // row 2k: w[10-j] -> slot j
                float wt = gw.w[10 - j];
                pendP[c][j] = fmaf(wt, hP[0][c], pendP[c][j]);
                pendQ[c][j] = fmaf(wt, hQ[0][c], pendQ[c][j]);
                pendU[c][j] = fmaf(wt, hU[0][c], pendU[c][j]);
                pendV[c][j] = fmaf(wt, hV[0][c], pendV[c][j]);
            }
            #pragma unroll
            for (int j = 1; j <= 11; ++j) {          // row 2k+1: w[11-j] -> slot j
                float wt = gw.w[11 - j];
                pendP[c][j] = fmaf(wt, hP[1][c], pendP[c][j]);
                pendQ[c][j] = fmaf(wt, hQ[1][c], pendQ[c][j]);
                pendU[c][j] = fmaf(wt, hU[1][c], pendU[c][j]);
                pendV[c][j] = fmaf(wt, hV[1][c], pendV[c][j]);
            }
        }

        // ---- emit 2 finished output rows x 2 cols (x2-rescaled, exact) ----
        #pragma unroll
        for (int e = 0; e < 2; ++e) {
            int rel = 2 * k - 10 + e;
            bool rowok = (unsigned)rel < (unsigned)rowsOut;
            #pragma unroll
            for (int c = 0; c < 2; ++c) {
                float p = pendP[c][e], q = pendQ[c][e];
                float uu = pendU[c][e], vv = pendV[c][e];
                float p2 = p * p, q2 = q * q;
                float A = p2 - q2;                       // 2*(2 mu12)
                float csn = (uu - vv - A) + C2x2;        // 2*(2 sigma12) + 2C2
                float csd = (uu + vv - p2 - q2) + C2x2;
                float cs  = csn * __builtin_amdgcn_rcpf(csd);
                float ss  = (A + C1x2) * __builtin_amdgcn_rcpf(p2 + q2 + C1x2) * cs;
                if (rowok && (c ? ok1 : ok0)) { ssum += ss; csum += cs; }
            }
        }

        // ---- shift rings by 2 slots ----
        #pragma unroll
        for (int c = 0; c < 2; ++c) {
            #pragma unroll
            for (int j = 0; j < 10; ++j) {
                pendP[c][j] = pendP[c][j + 2]; pendQ[c][j] = pendQ[c][j + 2];
                pendU[c][j] = pendU[c][j + 2]; pendV[c][j] = pendV[c][j + 2];
            }
            pendP[c][10] = 0.f; pendP[c][11] = 0.f;
            pendQ[c][10] = 0.f; pendQ[c][11] = 0.f;
            pendU[c][10] = 0.f; pendU[c][11] = 0.f;
            pendV[c][10] = 0.f; pendV[c][11] = 0.f;
        }

        // ---- 2x2 pool from registers (thread's col pair = 1 pooled output) ----
        if (doPool && k < (rps >> 1)) {
            float sa = u0save[0].x + u0save[0].z + u0save[1].x + u0save[1].z;
            float sb = u0save[0].y + u0save[0].w + u0save[1].y + u0save[1].w;
            int prow = (oy0 >> 1) + k;
            size_t o = (size_t)ch * halfS * halfS + (size_t)prow * halfS + lt;
            poolX[o] = 0.125f * (sa + sb);
            poolY[o] = 0.125f * (sa - sb);
        }

        // ---- stage next rows (vmcnt drain lives here, after all compute) ----
        if (k + 1 < NIT) {
            write_slot(sl ^ 1);
            if (k + 2 < NIT) issue(oy0 + 2 * (k + 2));
        }
        __syncthreads();
    }

    // ---- per-channel-subgroup reduction + atomic accumulate ----
    {
        int rw = (tpc < 64) ? tpc : 64;
        for (int off = rw >> 1; off > 0; off >>= 1) {
            ssum += __shfl_down(ssum, off);
            csum += __shfl_down(csum, off);
        }
        if ((lt & 63) == 0) {
            atomicAdd(&accum[ch], ssum);
            atomicAdd(&accum[96 + ch], csum);
        }
    }
}

__global__ void finalize_kernel(const float* __restrict__ accum, float* __restrict__ out)
{
    __shared__ float red[2];
    const int t = threadIdx.x;   // 128 threads
    const float w[5]   = {0.0448f, 0.2856f, 0.3001f, 0.2363f, 0.1333f};
    const float inv[5] = {1.f / (502.f * 502.f), 1.f / (246.f * 246.f),
                          1.f / (118.f * 118.f), 1.f / (54.f * 54.f),
                          1.f / (22.f * 22.f)};
    float ms = 0.f;
    if (t < 96) {
        ms = 1.f;
        #pragma unroll
        for (int l = 0; l < 5; ++l) {
            float v = (l < 4) ? accum[l * 192 + 96 + t] : accum[l * 192 + t];
            v *= inv[l];
            v = fmaxf(v, 0.f);
            ms *= powf(v, w[l]);
        }
    }
    for (int off = 32; off > 0; off >>= 1) ms += __shfl_down(ms, off);
    int wid = t >> 6, lane = t & 63;
    if (lane == 0) red[wid] = ms;
    __syncthreads();
    if (t == 0) out[0] = 1.f - (red[0] + red[1]) * (1.f / 96.f);
}

extern "C" void kernel_launch(void* const* d_in, const int* in_sizes, int n_in,
                              void* d_out, int out_size, void* d_ws, size_t ws_size,
                              hipStream_t stream)
{
    (void)in_sizes; (void)n_in; (void)out_size; (void)ws_size;
    const float* X = (const float*)d_in[0];
    const float* Y = (const float*)d_in[1];
    float* out = (float*)d_out;
    float* ws  = (float*)d_ws;

    // Gaussian window (size 11, sigma 1.5), normalized
    GWin gw;
    {
        double g[11], s = 0.0;
        for (int i = 0; i < 11; ++i) { double d = i - 5; g[i] = exp(-(d * d) / 4.5); s += g[i]; }
        for (int i = 0; i < 11; ++i) gw.w[i] = (float)(g[i] / s);
    }

    // workspace layout (floats)
    float* accum = ws;                 // 5 levels * 192
    size_t off = 1024;
    float* p1x = ws + off; off += (size_t)96 * 256 * 256;
    float* p1y = ws + off; off += (size_t)96 * 256 * 256;
    float* p2x = ws + off; off += (size_t)96 * 128 * 128;
    float* p2y = ws + off; off += (size_t)96 * 128 * 128;
    float* p3x = ws + off; off += (size_t)96 * 64 * 64;
    float* p3y = ws + off; off += (size_t)96 * 64 * 64;
    float* p4x = ws + off; off += (size_t)96 * 32 * 32;
    float* p4y = ws + off; off += (size_t)96 * 32 * 32;

    hipMemsetAsync(accum, 0, 5 * 192 * sizeof(float), stream);

    auto launch = [&](const float* x, const float* y, float* px_, float* py_,
                      float* acc, int S, int outS, int pool, int rps, int tpcLog) {
        int nsub = 256 >> tpcLog;
        dim3 g((outS + rps - 1) / rps, 1, 96 / nsub);
        ssim_rows_kernel<<<g, 256, 0, stream>>>(x, y, px_, py_, acc, S, outS, pool,
                                                rps, tpcLog, gw);
    };

    // per level: tpc = S/2 threads per channel; strips*rps >= S keeps pool covered
    launch(X,   Y,   p1x, p1y, accum + 0,   512, 502, 1, 64, 8);  // 8 strips x 96
    launch(p1x, p1y, p2x, p2y, accum + 192, 256, 246, 1, 32, 7);  // 8 x 48
    launch(p2x, p2y, p3x, p3y, accum + 384, 128, 118, 1, 16, 6);  // 8 x 24
    launch(p3x, p3y, p4x, p4y, accum + 576, 64,  54,  1, 16, 5);  // 4 x 12
    launch(p4x, p4y, nullptr, nullptr, accum + 768, 32, 22, 0, 22, 4);  // 1 x 6

    finalize_kernel<<<1, 128, 0, stream>>>(accum, out);
}